// Round 1
// baseline (324.880 us; speedup 1.0000x reference)
//
#include <hip/hip_runtime.h>
#include <hip/hip_bf16.h>
#include <math.h>

typedef __bf16 bf16;
typedef __bf16 bf16x8 __attribute__((ext_vector_type(8)));
typedef __bf16 bf16x4 __attribute__((ext_vector_type(4)));
typedef float f32x4 __attribute__((ext_vector_type(4)));

#define MFMA16(a, b, c) __builtin_amdgcn_mfma_f32_16x16x32_bf16(a, b, c, 0, 0, 0)

// ---------------------------------------------------------------------------
// Kernel 1: GroupNorm  x(fp32, b,c,hw) -> h(bf16, b,c,hw)
// one block per (batch, group): 8 channels x 4096 = 32768 elements
// ---------------------------------------------------------------------------
__global__ __launch_bounds__(256) void gn_kernel(
    const float* __restrict__ x, const float* __restrict__ gw,
    const float* __restrict__ gb, bf16* __restrict__ h) {
  const int bg = blockIdx.x;            // 0..127
  const int b = bg >> 5, g = bg & 31;
  const size_t base = (size_t)(b * 256 + g * 8) * 4096;
  const float* xp = x + base;
  bf16* hp = h + base;
  const int tid = threadIdx.x;

  float s = 0.f, ss = 0.f;
  for (int i = tid * 4; i < 32768; i += 1024) {
    float4 v = *(const float4*)(xp + i);
    s += v.x + v.y + v.z + v.w;
    ss += v.x * v.x + v.y * v.y + v.z * v.z + v.w * v.w;
  }
#pragma unroll
  for (int off = 32; off; off >>= 1) {
    s += __shfl_down(s, off);
    ss += __shfl_down(ss, off);
  }
  __shared__ float red[8];
  if ((tid & 63) == 0) {
    red[(tid >> 6) * 2] = s;
    red[(tid >> 6) * 2 + 1] = ss;
  }
  __syncthreads();
  s = red[0] + red[2] + red[4] + red[6];
  ss = red[1] + red[3] + red[5] + red[7];
  const float mean = s * (1.f / 32768.f);
  const float var = ss * (1.f / 32768.f) - mean * mean;
  const float rstd = rsqrtf(var + 1e-5f);

  for (int i = tid * 4; i < 32768; i += 1024) {
    float4 v = *(const float4*)(xp + i);
    int c = g * 8 + (i >> 12);
    float a = gw[c] * rstd;
    float b2 = gb[c] - mean * a;
    bf16x4 o;
    o[0] = (bf16)(v.x * a + b2);
    o[1] = (bf16)(v.y * a + b2);
    o[2] = (bf16)(v.z * a + b2);
    o[3] = (bf16)(v.w * a + b2);
    *(bf16x4*)(hp + i) = o;
  }
}

// ---------------------------------------------------------------------------
// Kernel 2: QKV GEMM  qkv[o,p] = sum_c w[o,c]*h[c,p] + bias[o]
// outputs: q -> qt(b,p,c) pixel-major, k -> kt(b,p,c), v -> vcm(b,c,p)
// 64x64 tile per block, 4 waves each 32x32, K-step 32
// ---------------------------------------------------------------------------
__global__ __launch_bounds__(256) void qkv_gemm(
    const bf16* __restrict__ h, const float* __restrict__ w,
    const float* __restrict__ bias, bf16* __restrict__ qt,
    bf16* __restrict__ kt, bf16* __restrict__ vcm) {
  const int b = blockIdx.z;
  const int o0 = blockIdx.y * 64;
  const int p0 = blockIdx.x * 64;
  __shared__ bf16 Alds[64][56];  // o rows x c cols (stride 112B: odd multiple of 16B)
  __shared__ bf16 Blds[64][56];  // p rows x c cols
  const int tid = threadIdx.x;
  const int lane = tid & 63, wid = tid >> 6;
  const int lr = lane & 15, lg = lane >> 4;
  const int wm = wid >> 1, wn = wid & 1;
  const bf16* hb = h + (size_t)b * 256 * 4096;

  f32x4 acc[2][2] = {};

  for (int k0 = 0; k0 < 256; k0 += 32) {
    // stage A (fp32 -> bf16): 64x32
    {
      int row = tid >> 2, c8 = (tid & 3) * 8;
      const float* src = w + (size_t)(o0 + row) * 256 + k0 + c8;
      float4 v0 = *(const float4*)src;
      float4 v1 = *(const float4*)(src + 4);
      bf16x8 bv;
      bv[0] = (bf16)v0.x; bv[1] = (bf16)v0.y; bv[2] = (bf16)v0.z; bv[3] = (bf16)v0.w;
      bv[4] = (bf16)v1.x; bv[5] = (bf16)v1.y; bv[6] = (bf16)v1.z; bv[7] = (bf16)v1.w;
      *(bf16x8*)&Alds[row][c8] = bv;
    }
    // stage B with transpose: h[c, p] tile (32c x 64p) -> Blds[p][c]
    {
      int cc = tid >> 3, p8 = (tid & 7) * 8;
      bf16x8 v = *(const bf16x8*)(hb + (size_t)(k0 + cc) * 4096 + p0 + p8);
#pragma unroll
      for (int e = 0; e < 8; ++e) Blds[p8 + e][cc] = v[e];
    }
    __syncthreads();
    bf16x8 af[2], bfr[2];
#pragma unroll
    for (int mi = 0; mi < 2; ++mi)
      af[mi] = *(const bf16x8*)&Alds[wm * 32 + mi * 16 + lr][lg * 8];
#pragma unroll
    for (int ni = 0; ni < 2; ++ni)
      bfr[ni] = *(const bf16x8*)&Blds[wn * 32 + ni * 16 + lr][lg * 8];
#pragma unroll
    for (int mi = 0; mi < 2; ++mi)
#pragma unroll
      for (int ni = 0; ni < 2; ++ni)
        acc[mi][ni] = MFMA16(af[mi], bfr[ni], acc[mi][ni]);
    __syncthreads();
  }

  // epilogue: route to q/k/v
#pragma unroll
  for (int mi = 0; mi < 2; ++mi) {
#pragma unroll
    for (int ni = 0; ni < 2; ++ni) {
#pragma unroll
      for (int r = 0; r < 4; ++r) {
        int o = o0 + wm * 32 + mi * 16 + lg * 4 + r;
        int p = p0 + wn * 32 + ni * 16 + lr;
        float val = acc[mi][ni][r] + bias[o];
        if (o < 256) {
          qt[((size_t)b * 4096 + p) * 256 + o] = (bf16)val;
        } else if (o < 512) {
          kt[((size_t)b * 4096 + p) * 256 + (o - 256)] = (bf16)val;
        } else {
          vcm[((size_t)b * 256 + (o - 512)) * 4096 + p] = (bf16)val;
        }
      }
    }
  }
}

// ---------------------------------------------------------------------------
// Kernel 3: flash attention
// grid (64 qtiles, 4 batch), 256 threads = 4 waves, each wave owns 16 Q rows.
// Q kept in registers; K/V tiles (BN=32) staged in LDS; online softmax.
// att output pixel-major (b, p, c) bf16.
// ---------------------------------------------------------------------------
__global__ __launch_bounds__(256) void flash_attn(
    const bf16* __restrict__ qt, const bf16* __restrict__ kt,
    const bf16* __restrict__ vcm, bf16* __restrict__ att) {
  const int b = blockIdx.y;
  const int i0 = blockIdx.x * 64;
  __shared__ bf16 Klds[32][264];     // j rows x c cols (528B stride = 33x16B, odd)
  __shared__ bf16 Vlds[256][56];     // c rows x j cols (112B stride = 7x16B, odd)
  __shared__ bf16 Plds[4][16][56];   // per-wave P tile: i rows x j cols
  const int tid = threadIdx.x;
  const int lane = tid & 63, w = tid >> 6;
  const int lr = lane & 15, lg = lane >> 4;
  const bf16* qb = qt + (size_t)b * 4096 * 256;
  const bf16* kb = kt + (size_t)b * 4096 * 256;
  const bf16* vb = vcm + (size_t)b * 256 * 4096;

  // Q fragments: wave rows i0 + w*16 + [0,16)
  bf16x8 qa[8];
  const int ib = i0 + w * 16 + lr;
#pragma unroll
  for (int ks = 0; ks < 8; ++ks)
    qa[ks] = *(const bf16x8*)(qb + (size_t)ib * 256 + ks * 32 + lg * 8);

  float m[4] = {-INFINITY, -INFINITY, -INFINITY, -INFINITY};
  float l[4] = {0.f, 0.f, 0.f, 0.f};
  f32x4 accO[16] = {};

  for (int jt = 0; jt < 128; ++jt) {
    const int j0 = jt * 32;
    // stage K tile: 32 rows(j) x 256 cols(c)
#pragma unroll
    for (int it = 0; it < 4; ++it) {
      int chunk = tid + 256 * it;
      int row = chunk >> 5, c8 = (chunk & 31) * 8;
      *(bf16x8*)&Klds[row][c8] =
          *(const bf16x8*)(kb + (size_t)(j0 + row) * 256 + c8);
    }
    // stage V tile: 256 rows(c) x 32 cols(j)
#pragma unroll
    for (int it = 0; it < 4; ++it) {
      int chunk = tid + 256 * it;
      int row = chunk >> 2, j8 = (chunk & 3) * 8;
      *(bf16x8*)&Vlds[row][j8] =
          *(const bf16x8*)(vb + (size_t)row * 4096 + j0 + j8);
    }
    __syncthreads();

    // S = Q @ K^T  (16 rows x 32 cols per wave)
    f32x4 accS[2] = {};
#pragma unroll
    for (int ks = 0; ks < 8; ++ks) {
#pragma unroll
      for (int nf = 0; nf < 2; ++nf) {
        bf16x8 kf = *(const bf16x8*)&Klds[nf * 16 + lr][ks * 32 + lg * 8];
        accS[nf] = MFMA16(qa[ks], kf, accS[nf]);
      }
    }

    // online softmax (rows owned by this lane: i = lg*4 + r)
    float pv[2][4], mx[4];
#pragma unroll
    for (int r = 0; r < 4; ++r) {
      float v0 = accS[0][r] * 0.0625f;
      float v1 = accS[1][r] * 0.0625f;
      pv[0][r] = v0; pv[1][r] = v1;
      float v = fmaxf(v0, v1);
      v = fmaxf(v, __shfl_xor(v, 1));
      v = fmaxf(v, __shfl_xor(v, 2));
      v = fmaxf(v, __shfl_xor(v, 4));
      v = fmaxf(v, __shfl_xor(v, 8));
      mx[r] = v;
    }
    float corr[4];
#pragma unroll
    for (int r = 0; r < 4; ++r) {
      float mn = fmaxf(m[r], mx[r]);
      corr[r] = __expf(m[r] - mn);
      m[r] = mn;
      float p0 = __expf(pv[0][r] - mn);
      float p1 = __expf(pv[1][r] - mn);
      pv[0][r] = p0; pv[1][r] = p1;
      float rsum = p0 + p1;
      rsum += __shfl_xor(rsum, 1);
      rsum += __shfl_xor(rsum, 2);
      rsum += __shfl_xor(rsum, 4);
      rsum += __shfl_xor(rsum, 8);
      l[r] = l[r] * corr[r] + rsum;
    }
#pragma unroll
    for (int cf = 0; cf < 16; ++cf)
#pragma unroll
      for (int r = 0; r < 4; ++r) accO[cf][r] *= corr[r];

    // write P (bf16) to per-wave LDS
#pragma unroll
    for (int nf = 0; nf < 2; ++nf)
#pragma unroll
      for (int r = 0; r < 4; ++r)
        Plds[w][lg * 4 + r][nf * 16 + lr] = (bf16)pv[nf][r];
    __syncthreads();

    // O += P @ V^T   (K-dim = j = 32)
    bf16x8 pa = *(const bf16x8*)&Plds[w][lr][lg * 8];
#pragma unroll
    for (int nf = 0; nf < 16; ++nf) {
      bf16x8 vf = *(const bf16x8*)&Vlds[nf * 16 + lr][lg * 8];
      accO[nf] = MFMA16(pa, vf, accO[nf]);
    }
    __syncthreads();
  }

  // epilogue: normalize and store pixel-major att[b][p][c]
  float inv[4];
#pragma unroll
  for (int r = 0; r < 4; ++r) inv[r] = 1.f / l[r];
  bf16* ob = att + (size_t)b * 4096 * 256;
#pragma unroll
  for (int nf = 0; nf < 16; ++nf)
#pragma unroll
    for (int r = 0; r < 4; ++r)
      ob[(size_t)(i0 + w * 16 + lg * 4 + r) * 256 + nf * 16 + lr] =
          (bf16)(accO[nf][r] * inv[r]);
}

// ---------------------------------------------------------------------------
// Kernel 4: proj GEMM + bias + residual
// out[b,o,p] = x[b,o,p] + bias[o] + sum_c w[o,c] * att[b,p,c]
// ---------------------------------------------------------------------------
__global__ __launch_bounds__(256) void proj_gemm(
    const bf16* __restrict__ att, const float* __restrict__ w,
    const float* __restrict__ bias, const float* __restrict__ x,
    float* __restrict__ out) {
  const int b = blockIdx.z;
  const int o0 = blockIdx.y * 64;
  const int p0 = blockIdx.x * 64;
  __shared__ bf16 Alds[64][56];  // o rows x c cols
  __shared__ bf16 Blds[64][56];  // p rows x c cols
  const int tid = threadIdx.x;
  const int lane = tid & 63, wid = tid >> 6;
  const int lr = lane & 15, lg = lane >> 4;
  const int wm = wid >> 1, wn = wid & 1;
  const bf16* ab = att + (size_t)b * 4096 * 256;

  f32x4 acc[2][2] = {};

  for (int k0 = 0; k0 < 256; k0 += 32) {
    {
      int row = tid >> 2, c8 = (tid & 3) * 8;
      const float* src = w + (size_t)(o0 + row) * 256 + k0 + c8;
      float4 v0 = *(const float4*)src;
      float4 v1 = *(const float4*)(src + 4);
      bf16x8 bv;
      bv[0] = (bf16)v0.x; bv[1] = (bf16)v0.y; bv[2] = (bf16)v0.z; bv[3] = (bf16)v0.w;
      bv[4] = (bf16)v1.x; bv[5] = (bf16)v1.y; bv[6] = (bf16)v1.z; bv[7] = (bf16)v1.w;
      *(bf16x8*)&Alds[row][c8] = bv;
    }
    {
      int pr = tid >> 2, c8 = (tid & 3) * 8;
      *(bf16x8*)&Blds[pr][c8] =
          *(const bf16x8*)(ab + (size_t)(p0 + pr) * 256 + k0 + c8);
    }
    __syncthreads();
    bf16x8 af[2], bfr[2];
#pragma unroll
    for (int mi = 0; mi < 2; ++mi)
      af[mi] = *(const bf16x8*)&Alds[wm * 32 + mi * 16 + lr][lg * 8];
#pragma unroll
    for (int ni = 0; ni < 2; ++ni)
      bfr[ni] = *(const bf16x8*)&Blds[wn * 32 + ni * 16 + lr][lg * 8];
#pragma unroll
    for (int mi = 0; mi < 2; ++mi)
#pragma unroll
      for (int ni = 0; ni < 2; ++ni)
        acc[mi][ni] = MFMA16(af[mi], bfr[ni], acc[mi][ni]);
    __syncthreads();
  }

#pragma unroll
  for (int mi = 0; mi < 2; ++mi) {
#pragma unroll
    for (int ni = 0; ni < 2; ++ni) {
#pragma unroll
      for (int r = 0; r < 4; ++r) {
        int o = o0 + wm * 32 + mi * 16 + lg * 4 + r;
        int p = p0 + wn * 32 + ni * 16 + lr;
        size_t idx = ((size_t)b * 256 + o) * 4096 + p;
        out[idx] = acc[mi][ni][r] + bias[o] + x[idx];
      }
    }
  }
}

// ---------------------------------------------------------------------------
extern "C" void kernel_launch(void* const* d_in, const int* in_sizes, int n_in,
                              void* d_out, int out_size, void* d_ws,
                              size_t ws_size, hipStream_t stream) {
  (void)in_sizes; (void)n_in; (void)out_size; (void)ws_size;
  const float* x = (const float*)d_in[0];
  const float* gn_w = (const float*)d_in[1];
  const float* gn_b = (const float*)d_in[2];
  const float* qkv_w = (const float*)d_in[3];
  const float* qkv_b = (const float*)d_in[4];
  const float* proj_w = (const float*)d_in[5];
  const float* proj_b = (const float*)d_in[6];
  float* out = (float*)d_out;

  char* ws = (char*)d_ws;
  bf16* h = (bf16*)(ws);                              // 8 MB  (b,c,p)
  bf16* qt = (bf16*)(ws + 8ull * 1024 * 1024);        // 8 MB  (b,p,c)
  bf16* kt = (bf16*)(ws + 16ull * 1024 * 1024);       // 8 MB  (b,p,c)
  bf16* vcm = (bf16*)(ws + 24ull * 1024 * 1024);      // 8 MB  (b,c,p)
  bf16* att = (bf16*)(ws + 32ull * 1024 * 1024);      // 8 MB  (b,p,c)

  gn_kernel<<<128, 256, 0, stream>>>(x, gn_w, gn_b, h);
  qkv_gemm<<<dim3(64, 12, 4), 256, 0, stream>>>(h, qkv_w, qkv_b, qt, kt, vcm);
  flash_attn<<<dim3(64, 4), 256, 0, stream>>>(qt, kt, vcm, att);
  proj_gemm<<<dim3(64, 4, 4), 256, 0, stream>>>(att, proj_w, proj_b, x, out);
}